// Round 5
// baseline (461.212 us; speedup 1.0000x reference)
//
#include <hip/hip_runtime.h>
#include <hip/hip_bf16.h>
#include <math.h>

#define NN 64
#define DD 128
#define PP 4800
#define KK 64
#define BPN 15          // blocks per sample n (960 blocks / 512 slots = best packing)
#define PB  320         // positions per block
#define CP  64          // positions per chunk
#define NCH 5           // chunks per block

#define WT  136         // w_s  row stride (halfwords)
#define XPT 136         // xpd  row stride (halfwords, chunk-swizzled columns)
#define XDT 72          // xdp  row stride
#define SAT 72          // sa_s row stride

// ws float offsets
#define PAGG_SZ  ((size_t)NN * BPN * KK * DD)   // 31.46 MB
#define PSSUM_SZ ((size_t)NN * BPN * KK)

// static LDS carve (63488 B total)
#define SM_W    0
#define SM_XPD  17408
#define SM_XDP  34816
#define SM_SA   53248
#define SM_RED  62464
#define SM_TOT  63488
// epilogue aliases (all < SM_SA, used only after main loop is done)
#define SM_AGG  0        // 64 * 132 floats = 33792 B
#define SM_SRED 33792    // 64 floats
#define SM_WSUM 34048    // 4 floats
#define SM_FLAG 34064    // 1 int

typedef __attribute__((ext_vector_type(8))) short bf16x8;
typedef __attribute__((ext_vector_type(4))) float f32x4;

__device__ __forceinline__ unsigned short f2bf(float f) {
  unsigned u = __float_as_uint(f);
  u += 0x7fffu + ((u >> 16) & 1u);  // RNE
  return (unsigned short)(u >> 16);
}
__device__ __forceinline__ unsigned pk2(float a, float b) {
  union { __hip_bfloat162 h2; unsigned u; } cv;
  cv.h2 = __float22bfloat162_rn(make_float2(a, b));  // low = a, high = b
  return cv.u;
}

// ---------------------------------------------------------------------------
// Single fused kernel. Main loop identical to round-3 (best measured):
// reg-prefetched staging (fp32->bf16, [d][p] + swizzled [p][d]), fp32 per-p
// ssq fused into staging, MFMA GEMM1 -> softmax -> MFMA GEMM2, 3 barriers
// per chunk, one slab flush per block. NEW: last block per n (device-scope
// ticket) reduces the 15 slabs and runs the full epilogue inline.
// ---------------------------------------------------------------------------
__global__ __launch_bounds__(256, 2) void main_kernel(const float* __restrict__ x,
                                                      const float* __restrict__ conv_w,
                                                      const float* __restrict__ cent,
                                                      float* __restrict__ pagg,
                                                      float* __restrict__ pssum,
                                                      int* __restrict__ tickets,
                                                      float* __restrict__ out) {
  __shared__ __align__(16) unsigned char smem[SM_TOT];
  unsigned short* w_s  = (unsigned short*)(smem + SM_W);
  unsigned short* xpd  = (unsigned short*)(smem + SM_XPD);
  unsigned short* xdp  = (unsigned short*)(smem + SM_XDP);
  unsigned short* sa_s = (unsigned short*)(smem + SM_SA);
  float*          red_s = (float*)(smem + SM_RED);

  const int b = blockIdx.x;
  const int n = b / BPN, sl = b % BPN;
  const int t = threadIdx.x, lane = t & 63, wv = t >> 6;
  const int lq = lane >> 4, ll = lane & 15;
  const int pb = t & 7, db = t >> 3;  // staging tile: p in [8pb,8pb+8), d in [4db,4db+4)

  // ---- stage conv_w -> bf16 LDS (once)
  {
    int k = t >> 2, h = t & 3;
    const float* wp = conv_w + k * DD + h * 32;
    unsigned short* dst = &w_s[k * WT + h * 32];
#pragma unroll
    for (int i = 0; i < 4; ++i) {
      float4 a = *(const float4*)(wp + 8 * i);
      float4 c = *(const float4*)(wp + 8 * i + 4);
      uint4 o = {pk2(a.x, a.y), pk2(a.z, a.w), pk2(c.x, c.y), pk2(c.z, c.w)};
      *(uint4*)&dst[8 * i] = o;
    }
  }
  if (t < 64) red_s[t] = 0.f;

  const float* xb = x + (size_t)n * DD * PP + (size_t)(4 * db) * PP + sl * PB + 8 * pb;

  float4 pf[8];
#pragma unroll
  for (int r = 0; r < 4; ++r) {
    pf[2 * r]     = *(const float4*)(xb + (size_t)r * PP);
    pf[2 * r + 1] = *(const float4*)(xb + (size_t)r * PP + 4);
  }

  f32x4 acc[8];
#pragma unroll
  for (int i = 0; i < 8; ++i) acc[i] = (f32x4){0.f, 0.f, 0.f, 0.f};
  float ssacc[16];
#pragma unroll
  for (int i = 0; i < 16; ++i) ssacc[i] = 0.f;

  for (int c = 0; c < NCH; ++c) {
    float4 cur[8];
#pragma unroll
    for (int i = 0; i < 8; ++i) cur[i] = pf[i];
    if (c + 1 < NCH) {  // prefetch next chunk; completes during this chunk's compute
      const float* xc = xb + (c + 1) * CP;
#pragma unroll
      for (int r = 0; r < 4; ++r) {
        pf[2 * r]     = *(const float4*)(xc + (size_t)r * PP);
        pf[2 * r + 1] = *(const float4*)(xc + (size_t)r * PP + 4);
      }
    }

    // ---- fp32 per-p partial sum-of-squares over this thread's 4 d-rows
    float sq[8];
#pragma unroll
    for (int h = 0; h < 2; ++h)
#pragma unroll
      for (int j = 0; j < 4; ++j) {
        float s = 0.f;
#pragma unroll
        for (int r = 0; r < 4; ++r) {
          float v = (&cur[2 * r + h].x)[j];
          s = fmaf(v, v, s);
        }
        sq[4 * h + j] = s;
      }
#pragma unroll
    for (int i = 0; i < 8; ++i) {  // reduce over the wave's 8 db values
      sq[i] += __shfl_xor(sq[i], 8);
      sq[i] += __shfl_xor(sq[i], 16);
      sq[i] += __shfl_xor(sq[i], 32);
    }

    __syncthreads();  // B1: xpd/xdp/sa_s free (prev GEMM2 done), red_s zeroed

    if (lane < 8) {  // one lane per p-block per wave adds its wave's partial
#pragma unroll
      for (int j = 0; j < 8; ++j) atomicAdd(&red_s[8 * lane + j], sq[j]);
    }

    // ---- convert + stage: xdp b128 rows, xpd transposed b64 (chunk-swizzled)
    {
      unsigned prow[4][4];
#pragma unroll
      for (int r = 0; r < 4; ++r) {
        const float4& a = cur[2 * r];
        const float4& c2 = cur[2 * r + 1];
        prow[r][0] = pk2(a.x, a.y);
        prow[r][1] = pk2(a.z, a.w);
        prow[r][2] = pk2(c2.x, c2.y);
        prow[r][3] = pk2(c2.z, c2.w);
        uint4 o = {prow[r][0], prow[r][1], prow[r][2], prow[r][3]};
        *(uint4*)&xdp[(4 * db + r) * XDT + 8 * pb] = o;
      }
      const int colh = (((db >> 1) ^ pb) << 3) + (db & 1) * 4;  // swizzled column
#pragma unroll
      for (int j2 = 0; j2 < 4; ++j2) {
        unsigned lo01 = __builtin_amdgcn_perm(prow[1][j2], prow[0][j2], 0x05040100u);
        unsigned hi01 = __builtin_amdgcn_perm(prow[1][j2], prow[0][j2], 0x07060302u);
        unsigned lo23 = __builtin_amdgcn_perm(prow[3][j2], prow[2][j2], 0x05040100u);
        unsigned hi23 = __builtin_amdgcn_perm(prow[3][j2], prow[2][j2], 0x07060302u);
        int p_e = 8 * pb + 2 * j2;
        *(uint2*)&xpd[p_e * XPT + colh]       = make_uint2(lo01, lo23);
        *(uint2*)&xpd[(p_e + 1) * XPT + colh] = make_uint2(hi01, hi23);
      }
    }
    __syncthreads();  // B2: staging + ssq visible

    // ---- GEMM1 (logits) + softmax over K=64 (in-register)
    {
      const int prow_ = wv * 16 + ll;
      const int swz = (2 * wv + (ll >> 3)) & 7;
      f32x4 lg[4];
#pragma unroll
      for (int kt = 0; kt < 4; ++kt) lg[kt] = (f32x4){0.f, 0.f, 0.f, 0.f};
#pragma unroll
      for (int ks = 0; ks < 4; ++ks) {
        bf16x8 bfrag = *(const bf16x8*)&xpd[prow_ * XPT + ((((ks << 2) | lq) ^ swz) << 3)];
#pragma unroll
        for (int kt = 0; kt < 4; ++kt) {
          bf16x8 afrag = *(const bf16x8*)&w_s[(kt * 16 + ll) * WT + ks * 32 + lq * 8];
          lg[kt] = __builtin_amdgcn_mfma_f32_16x16x32_bf16(afrag, bfrag, lg[kt], 0, 0, 0);
        }
      }
      float iv = 1.0f / fmaxf(sqrtf(red_s[prow_]), 1e-12f);
      float vals[16];
      float m = -1e30f;
#pragma unroll
      for (int kt = 0; kt < 4; ++kt)
#pragma unroll
        for (int r = 0; r < 4; ++r) {
          float v = lg[kt][r] * iv;
          vals[kt * 4 + r] = v;
          m = fmaxf(m, v);
        }
      m = fmaxf(m, __shfl_xor(m, 16));
      m = fmaxf(m, __shfl_xor(m, 32));
      float se = 0.f;
#pragma unroll
      for (int i = 0; i < 16; ++i) {
        float e = __expf(vals[i] - m);
        vals[i] = e;
        se += e;
      }
      se += __shfl_xor(se, 16);
      se += __shfl_xor(se, 32);
      float rinv = 1.0f / se;
      float r2 = rinv * iv;  // fold invn into sa for GEMM2
#pragma unroll
      for (int kt = 0; kt < 4; ++kt)
#pragma unroll
        for (int r = 0; r < 4; ++r) {
          float e = vals[kt * 4 + r];
          ssacc[kt * 4 + r] += e * rinv;
          sa_s[(kt * 16 + lq * 4 + r) * SAT + prow_] = f2bf(e * r2);
        }
    }
    __syncthreads();  // B3: sa visible
    if (c + 1 < NCH && t < 64) red_s[t] = 0.f;  // re-zero ssq for next chunk

    // ---- GEMM2: acc[k-tile = wv][dt] += SA * X^T over this chunk
#pragma unroll
    for (int ks = 0; ks < 2; ++ks) {
      bf16x8 afrag = *(const bf16x8*)&sa_s[(wv * 16 + ll) * SAT + ks * 32 + lq * 8];
#pragma unroll
      for (int dt = 0; dt < 8; ++dt) {
        bf16x8 bfrag = *(const bf16x8*)&xdp[(dt * 16 + ll) * XDT + ks * 32 + lq * 8];
        acc[dt] = __builtin_amdgcn_mfma_f32_16x16x32_bf16(afrag, bfrag, acc[dt], 0, 0, 0);
      }
    }
  }

  // ---- flush agg partial slab (C-layout: k = 16wv+4lq+r, d = 16dt+ll)
  {
    float* base = pagg + (size_t)(n * BPN + sl) * (KK * DD);
#pragma unroll
    for (int dt = 0; dt < 8; ++dt)
#pragma unroll
      for (int r = 0; r < 4; ++r)
        base[(16 * wv + 4 * lq + r) * DD + dt * 16 + ll] = acc[dt][r];
  }
  // ---- flush ssum partial
  __syncthreads();  // red_s GEMM1 reads done; reuse full red_s for partials
#pragma unroll
  for (int i = 0; i < 16; ++i) {
    float s = ssacc[i];
    s += __shfl_xor(s, 1);
    s += __shfl_xor(s, 2);
    s += __shfl_xor(s, 4);
    s += __shfl_xor(s, 8);
    if (ll == 0) red_s[wv * 64 + (i >> 2) * 16 + lq * 4 + (i & 3)] = s;
  }
  __syncthreads();
  if (t < 64)
    pssum[(n * BPN + sl) * KK + t] =
        red_s[t] + red_s[64 + t] + red_s[128 + t] + red_s[192 + t];

  // ---- ticket: last block of this n does the epilogue inline
  __threadfence();   // release: slab + pssum visible device-wide
  __syncthreads();   // all threads' stores + fences retired
  int* flag = (int*)(smem + SM_FLAG);
  if (t == 0) {
    int prev = atomicAdd(&tickets[n], 1);
    *flag = (prev == BPN - 1) ? 1 : 0;
  }
  __syncthreads();
  if (*flag == 0) return;
  __threadfence();   // acquire: see the other 14 blocks' slabs

  // ================= inline epilogue for this n =================
  float* agg_s = (float*)(smem + SM_AGG);   // [64][132]
  float* sred  = (float*)(smem + SM_SRED);
  float* wsum  = (float*)(smem + SM_WSUM);
  __syncthreads();  // main-loop LDS dead before aliasing

  // phase A: sum BPN slabs into LDS (coalesced float4)
#pragma unroll
  for (int it = 0; it < 8; ++it) {
    int idx = t + 256 * it;  // float4 index 0..2047
    float4 a = {0.f, 0.f, 0.f, 0.f};
    const float4* base = (const float4*)(pagg + (size_t)n * BPN * (KK * DD));
    for (int s = 0; s < BPN; ++s) {
      float4 v = base[(size_t)s * (KK * DD / 4) + idx];
      a.x += v.x; a.y += v.y; a.z += v.z; a.w += v.w;
    }
    int row = idx >> 5, col = (idx & 31) * 4;
    *(float4*)&agg_s[row * 132 + col] = a;
  }
  if (t < KK) {
    float s = 0.f;
    for (int ss = 0; ss < BPN; ++ss) s += pssum[(n * BPN + ss) * KK + t];
    sred[t] = s;
  }
  __syncthreads();

  // phase B: vlad = agg - ssum*cent; intra-norm; global norm; store
  {
    const int k = t >> 2, j = t & 3;
    const float* ap = &agg_s[k * 132 + 32 * j];
    const float* cp = cent + (size_t)k * DD + 32 * j;
    const float sk = sred[k];

    float v[32];
    float ss = 0.f;
#pragma unroll
    for (int i = 0; i < 32; i += 4) {
      float4 a4 = *(const float4*)(ap + i);
      float4 c4 = *(const float4*)(cp + i);
      v[i + 0] = fmaf(-sk, c4.x, a4.x);
      v[i + 1] = fmaf(-sk, c4.y, a4.y);
      v[i + 2] = fmaf(-sk, c4.z, a4.z);
      v[i + 3] = fmaf(-sk, c4.w, a4.w);
      ss = fmaf(v[i + 0], v[i + 0], ss);
      ss = fmaf(v[i + 1], v[i + 1], ss);
      ss = fmaf(v[i + 2], v[i + 2], ss);
      ss = fmaf(v[i + 3], v[i + 3], ss);
    }
    ss += __shfl_xor(ss, 1);
    ss += __shfl_xor(ss, 2);
    float rinv = 1.0f / fmaxf(sqrtf(ss), 1e-12f);

    float gp = 0.f;
#pragma unroll
    for (int i = 0; i < 32; ++i) {
      v[i] *= rinv;
      gp = fmaf(v[i], v[i], gp);
    }
#pragma unroll
    for (int o = 1; o < 64; o <<= 1) gp += __shfl_xor(gp, o);
    if ((t & 63) == 0) wsum[t >> 6] = gp;
    __syncthreads();
    float g = wsum[0] + wsum[1] + wsum[2] + wsum[3];
    float ginv = 1.0f / fmaxf(sqrtf(g), 1e-12f);

    float* op = out + (size_t)n * KK * DD + (size_t)k * DD + 32 * j;
#pragma unroll
    for (int i = 0; i < 32; i += 4) {
      float4 o;
      o.x = v[i + 0] * ginv;
      o.y = v[i + 1] * ginv;
      o.z = v[i + 2] * ginv;
      o.w = v[i + 3] * ginv;
      *(float4*)(op + i) = o;
    }
  }
}

extern "C" void kernel_launch(void* const* d_in, const int* in_sizes, int n_in,
                              void* d_out, int out_size, void* d_ws, size_t ws_size,
                              hipStream_t stream) {
  const float* x      = (const float*)d_in[0];
  const float* conv_w = (const float*)d_in[1];
  const float* cent   = (const float*)d_in[2];
  float* out = (float*)d_out;
  float* ws  = (float*)d_ws;

  float* pagg  = ws;
  float* pssum = pagg + PAGG_SZ;
  int* tickets = (int*)(pssum + PSSUM_SZ);

  hipMemsetAsync(tickets, 0, NN * sizeof(int), stream);
  main_kernel<<<NN * BPN, 256, 0, stream>>>(x, conv_w, cent, pagg, pssum, tickets, out);
}

// Round 6
// 248.851 us; speedup vs baseline: 1.8534x; 1.8534x over previous
//
#include <hip/hip_runtime.h>
#include <hip/hip_bf16.h>
#include <math.h>

#define NN 64
#define DD 128
#define PP 4800
#define KK 64
#define BPN 15          // blocks per sample n (960 blocks; best measured packing)
#define PB  320         // positions per block
#define CP  64          // positions per chunk
#define NCH 5           // chunks per block

#define WT  136         // w_s  row stride (halfwords)
#define XPT 136         // xpd  row stride (halfwords, chunk-swizzled columns)
#define XDT 72          // xdp  row stride
#define SAT 72          // sa   row stride (aliased into xpd storage)

// ws float offsets
#define PAGG_SZ  ((size_t)NN * BPN * KK * DD)   // 31.46 MB
#define PSSUM_SZ ((size_t)NN * BPN * KK)
#define VTMP_SZ  ((size_t)NN * KK * DD)

typedef __attribute__((ext_vector_type(8))) short bf16x8;
typedef __attribute__((ext_vector_type(4))) float f32x4;

__device__ __forceinline__ unsigned short f2bf(float f) {
  unsigned u = __float_as_uint(f);
  u += 0x7fffu + ((u >> 16) & 1u);  // RNE
  return (unsigned short)(u >> 16);
}
__device__ __forceinline__ unsigned pk2(float a, float b) {
  union { __hip_bfloat162 h2; unsigned u; } cv;
  cv.h2 = __float22bfloat162_rn(make_float2(a, b));  // low = a, high = b
  return cv.u;
}

// ---------------------------------------------------------------------------
// Fused main (round-3 structure, BPN=15): reg-prefetched staging (fp32->bf16,
// [d][p] + swizzled [p][d]), fp32 per-p ssq fused into staging, MFMA GEMM1 ->
// softmax -> MFMA GEMM2. sa ALIASED into xpd's LDS (extra barrier makes it
// safe) -> 53 KB LDS -> 3 blocks/CU. One partial-slab flush per block.
// NO device-scope fences in-kernel (round-5 showed they cost ~270 us).
// ---------------------------------------------------------------------------
__global__ __launch_bounds__(256, 3) void main_kernel(const float* __restrict__ x,
                                                      const float* __restrict__ conv_w,
                                                      float* __restrict__ pagg,
                                                      float* __restrict__ pssum) {
  __shared__ __align__(16) unsigned short w_s[KK * WT];    // 17408 B
  __shared__ __align__(16) unsigned short xpd[KK * XPT];   // 17408 B (sa aliases base)
  __shared__ __align__(16) unsigned short xdp[DD * XDT];   // 18432 B
  __shared__ float red_s[256];  // [0,64): per-p ssq accumulator; flush: 256 partials

  unsigned short* sa_s = xpd;   // 64*72*2 = 9216 B <= 17408, reused after GEMM1

  const int b = blockIdx.x;
  const int n = b / BPN, sl = b % BPN;
  const int t = threadIdx.x, lane = t & 63, wv = t >> 6;
  const int lq = lane >> 4, ll = lane & 15;
  const int pb = t & 7, db = t >> 3;  // staging tile: p in [8pb,8pb+8), d in [4db,4db+4)

  // ---- stage conv_w -> bf16 LDS (once)
  {
    int k = t >> 2, h = t & 3;
    const float* wp = conv_w + k * DD + h * 32;
    unsigned short* dst = &w_s[k * WT + h * 32];
#pragma unroll
    for (int i = 0; i < 4; ++i) {
      float4 a = *(const float4*)(wp + 8 * i);
      float4 c = *(const float4*)(wp + 8 * i + 4);
      uint4 o = {pk2(a.x, a.y), pk2(a.z, a.w), pk2(c.x, c.y), pk2(c.z, c.w)};
      *(uint4*)&dst[8 * i] = o;
    }
  }
  if (t < 64) red_s[t] = 0.f;

  const float* xb = x + (size_t)n * DD * PP + (size_t)(4 * db) * PP + sl * PB + 8 * pb;

  float4 pf[8];
#pragma unroll
  for (int r = 0; r < 4; ++r) {
    pf[2 * r]     = *(const float4*)(xb + (size_t)r * PP);
    pf[2 * r + 1] = *(const float4*)(xb + (size_t)r * PP + 4);
  }

  f32x4 acc[8];
#pragma unroll
  for (int i = 0; i < 8; ++i) acc[i] = (f32x4){0.f, 0.f, 0.f, 0.f};
  float ssacc[16];
#pragma unroll
  for (int i = 0; i < 16; ++i) ssacc[i] = 0.f;

  for (int c = 0; c < NCH; ++c) {
    float4 cur[8];
#pragma unroll
    for (int i = 0; i < 8; ++i) cur[i] = pf[i];
    if (c + 1 < NCH) {  // prefetch next chunk; completes during this chunk's compute
      const float* xc = xb + (c + 1) * CP;
#pragma unroll
      for (int r = 0; r < 4; ++r) {
        pf[2 * r]     = *(const float4*)(xc + (size_t)r * PP);
        pf[2 * r + 1] = *(const float4*)(xc + (size_t)r * PP + 4);
      }
    }

    // ---- fp32 per-p partial sum-of-squares over this thread's 4 d-rows
    float sq[8];
#pragma unroll
    for (int h = 0; h < 2; ++h)
#pragma unroll
      for (int j = 0; j < 4; ++j) {
        float s = 0.f;
#pragma unroll
        for (int r = 0; r < 4; ++r) {
          float v = (&cur[2 * r + h].x)[j];
          s = fmaf(v, v, s);
        }
        sq[4 * h + j] = s;
      }
#pragma unroll
    for (int i = 0; i < 8; ++i) {  // reduce over the wave's 8 db values
      sq[i] += __shfl_xor(sq[i], 8);
      sq[i] += __shfl_xor(sq[i], 16);
      sq[i] += __shfl_xor(sq[i], 32);
    }

    __syncthreads();  // B1: xpd(sa)/xdp free (prev GEMM2 done), red_s zeroed

    if (lane < 8) {  // one lane per p-block per wave adds its wave's partial
#pragma unroll
      for (int j = 0; j < 8; ++j) atomicAdd(&red_s[8 * lane + j], sq[j]);
    }

    // ---- convert + stage: xdp b128 rows, xpd transposed b64 (chunk-swizzled)
    {
      unsigned prow[4][4];
#pragma unroll
      for (int r = 0; r < 4; ++r) {
        const float4& a = cur[2 * r];
        const float4& c2 = cur[2 * r + 1];
        prow[r][0] = pk2(a.x, a.y);
        prow[r][1] = pk2(a.z, a.w);
        prow[r][2] = pk2(c2.x, c2.y);
        prow[r][3] = pk2(c2.z, c2.w);
        uint4 o = {prow[r][0], prow[r][1], prow[r][2], prow[r][3]};
        *(uint4*)&xdp[(4 * db + r) * XDT + 8 * pb] = o;
      }
      const int colh = (((db >> 1) ^ pb) << 3) + (db & 1) * 4;  // swizzled column
#pragma unroll
      for (int j2 = 0; j2 < 4; ++j2) {
        unsigned lo01 = __builtin_amdgcn_perm(prow[1][j2], prow[0][j2], 0x05040100u);
        unsigned hi01 = __builtin_amdgcn_perm(prow[1][j2], prow[0][j2], 0x07060302u);
        unsigned lo23 = __builtin_amdgcn_perm(prow[3][j2], prow[2][j2], 0x05040100u);
        unsigned hi23 = __builtin_amdgcn_perm(prow[3][j2], prow[2][j2], 0x07060302u);
        int p_e = 8 * pb + 2 * j2;
        *(uint2*)&xpd[p_e * XPT + colh]       = make_uint2(lo01, lo23);
        *(uint2*)&xpd[(p_e + 1) * XPT + colh] = make_uint2(hi01, hi23);
      }
    }
    __syncthreads();  // B2: staging + ssq visible

    // ---- GEMM1 (logits) + softmax over K=64 (in-register)
    const int prow_ = wv * 16 + ll;
    float vals[16];
    float rinv_se, iv;
    {
      const int swz = (2 * wv + (ll >> 3)) & 7;
      f32x4 lg[4];
#pragma unroll
      for (int kt = 0; kt < 4; ++kt) lg[kt] = (f32x4){0.f, 0.f, 0.f, 0.f};
#pragma unroll
      for (int ks = 0; ks < 4; ++ks) {
        bf16x8 bfrag = *(const bf16x8*)&xpd[prow_ * XPT + ((((ks << 2) | lq) ^ swz) << 3)];
#pragma unroll
        for (int kt = 0; kt < 4; ++kt) {
          bf16x8 afrag = *(const bf16x8*)&w_s[(kt * 16 + ll) * WT + ks * 32 + lq * 8];
          lg[kt] = __builtin_amdgcn_mfma_f32_16x16x32_bf16(afrag, bfrag, lg[kt], 0, 0, 0);
        }
      }
      iv = 1.0f / fmaxf(sqrtf(red_s[prow_]), 1e-12f);
      float m = -1e30f;
#pragma unroll
      for (int kt = 0; kt < 4; ++kt)
#pragma unroll
        for (int r = 0; r < 4; ++r) {
          float v = lg[kt][r] * iv;
          vals[kt * 4 + r] = v;
          m = fmaxf(m, v);
        }
      m = fmaxf(m, __shfl_xor(m, 16));
      m = fmaxf(m, __shfl_xor(m, 32));
      float se = 0.f;
#pragma unroll
      for (int i = 0; i < 16; ++i) {
        float e = __expf(vals[i] - m);
        vals[i] = e;
        se += e;
      }
      se += __shfl_xor(se, 16);
      se += __shfl_xor(se, 32);
      rinv_se = 1.0f / se;
    }
    __syncthreads();  // B3: all xpd reads done -> safe to overwrite with sa

    {
      float r2 = rinv_se * iv;  // fold invn into sa for GEMM2
#pragma unroll
      for (int kt = 0; kt < 4; ++kt)
#pragma unroll
        for (int r = 0; r < 4; ++r) {
          float e = vals[kt * 4 + r];
          ssacc[kt * 4 + r] += e * rinv_se;
          sa_s[(kt * 16 + lq * 4 + r) * SAT + prow_] = f2bf(e * r2);
        }
    }
    if (c + 1 < NCH && t < 64) red_s[t] = 0.f;  // re-zero ssq for next chunk
    __syncthreads();  // B4: sa visible

    // ---- GEMM2: acc[k-tile = wv][dt] += SA * X^T over this chunk
#pragma unroll
    for (int ks = 0; ks < 2; ++ks) {
      bf16x8 afrag = *(const bf16x8*)&sa_s[(wv * 16 + ll) * SAT + ks * 32 + lq * 8];
#pragma unroll
      for (int dt = 0; dt < 8; ++dt) {
        bf16x8 bfrag = *(const bf16x8*)&xdp[(dt * 16 + ll) * XDT + ks * 32 + lq * 8];
        acc[dt] = __builtin_amdgcn_mfma_f32_16x16x32_bf16(afrag, bfrag, acc[dt], 0, 0, 0);
      }
    }
  }

  // ---- flush agg partial slab (C-layout: k = 16wv+4lq+r, d = 16dt+ll)
  {
    float* base = pagg + (size_t)(n * BPN + sl) * (KK * DD);
#pragma unroll
    for (int dt = 0; dt < 8; ++dt)
#pragma unroll
      for (int r = 0; r < 4; ++r)
        base[(16 * wv + 4 * lq + r) * DD + dt * 16 + ll] = acc[dt][r];
  }
  // ---- flush ssum
  __syncthreads();  // red_s[0:64) reads done; reuse full red_s for partials
#pragma unroll
  for (int i = 0; i < 16; ++i) {
    float s = ssacc[i];
    s += __shfl_xor(s, 1);
    s += __shfl_xor(s, 2);
    s += __shfl_xor(s, 4);
    s += __shfl_xor(s, 8);
    if (ll == 0) red_s[wv * 64 + (i >> 2) * 16 + lq * 4 + (i & 3)] = s;
  }
  __syncthreads();
  if (t < 64)
    pssum[(n * BPN + sl) * KK + t] =
        red_s[t] + red_s[64 + t] + red_s[128 + t] + red_s[192 + t];
}

// ---------------------------------------------------------------------------
// Epilogue 1 (512 blocks): reduce BPN slabs, vlad = agg - ssum*cent,
// intra-normalize per k, store to vtmp + per-block global-norm partial.
// ---------------------------------------------------------------------------
__global__ __launch_bounds__(256) void ep1_kernel(const float* __restrict__ pagg,
                                                  const float* __restrict__ pssum,
                                                  const float* __restrict__ cent,
                                                  float* __restrict__ vtmp,
                                                  float* __restrict__ gsum) {
  __shared__ float wsum[4];
  const int blk = blockIdx.x;
  const int n = blk >> 3, kg = blk & 7;
  const int t = threadIdx.x;
  const int kl = t >> 5, c32 = t & 31;  // k-row in block, 32 lanes per row
  const int k = kg * 8 + kl;
  const size_t off = (size_t)k * DD + c32 * 4;

  const float* base = pagg + (size_t)n * BPN * (KK * DD) + off;
  float4 a = {0.f, 0.f, 0.f, 0.f};
  for (int s = 0; s < BPN; ++s) {
    float4 v = *(const float4*)(base + (size_t)s * (KK * DD));
    a.x += v.x; a.y += v.y; a.z += v.z; a.w += v.w;
  }
  float sk = 0.f;
  for (int s = 0; s < BPN; ++s) sk += pssum[(n * BPN + s) * KK + k];

  float4 c4 = *(const float4*)(cent + off);
  float4 v;
  v.x = fmaf(-sk, c4.x, a.x);
  v.y = fmaf(-sk, c4.y, a.y);
  v.z = fmaf(-sk, c4.z, a.z);
  v.w = fmaf(-sk, c4.w, a.w);

  float pss = v.x * v.x + v.y * v.y + v.z * v.z + v.w * v.w;  // thread partial
  float ss = pss;
  ss += __shfl_xor(ss, 1);
  ss += __shfl_xor(ss, 2);
  ss += __shfl_xor(ss, 4);
  ss += __shfl_xor(ss, 8);
  ss += __shfl_xor(ss, 16);  // row total (32 lanes per k-row)
  float rinv = 1.0f / fmaxf(sqrtf(ss), 1e-12f);
  v.x *= rinv; v.y *= rinv; v.z *= rinv; v.w *= rinv;
  *(float4*)(vtmp + (size_t)n * (KK * DD) + off) = v;

  float gp = pss * rinv * rinv;  // post-norm partial for global L2
#pragma unroll
  for (int o = 1; o < 64; o <<= 1) gp += __shfl_xor(gp, o);
  if ((t & 63) == 0) wsum[t >> 6] = gp;
  __syncthreads();
  if (t == 0) gsum[blk] = wsum[0] + wsum[1] + wsum[2] + wsum[3];
}

// ---------------------------------------------------------------------------
// Epilogue 2 (64 blocks): global L2 normalize and store.
// ---------------------------------------------------------------------------
__global__ __launch_bounds__(256) void ep2_kernel(const float* __restrict__ vtmp,
                                                  const float* __restrict__ gsum,
                                                  float* __restrict__ out) {
  const int n = blockIdx.x, t = threadIdx.x;
  const float* gs = gsum + n * 8;
  float g = gs[0] + gs[1] + gs[2] + gs[3] + gs[4] + gs[5] + gs[6] + gs[7];
  float ginv = 1.0f / fmaxf(sqrtf(g), 1e-12f);
  const float4* vi = (const float4*)(vtmp + (size_t)n * (KK * DD));
  float4* vo = (float4*)(out + (size_t)n * (KK * DD));
#pragma unroll
  for (int it = 0; it < 8; ++it) {
    int idx = t + 256 * it;
    float4 f = vi[idx];
    f.x *= ginv; f.y *= ginv; f.z *= ginv; f.w *= ginv;
    vo[idx] = f;
  }
}

extern "C" void kernel_launch(void* const* d_in, const int* in_sizes, int n_in,
                              void* d_out, int out_size, void* d_ws, size_t ws_size,
                              hipStream_t stream) {
  const float* x      = (const float*)d_in[0];
  const float* conv_w = (const float*)d_in[1];
  const float* cent   = (const float*)d_in[2];
  float* out = (float*)d_out;
  float* ws  = (float*)d_ws;

  float* pagg  = ws;
  float* pssum = pagg + PAGG_SZ;
  float* vtmp  = pssum + PSSUM_SZ;
  float* gsum  = vtmp + VTMP_SZ;

  main_kernel<<<NN * BPN, 256, 0, stream>>>(x, conv_w, pagg, pssum);
  ep1_kernel<<<NN * 8, 256, 0, stream>>>(pagg, pssum, cent, vtmp, gsum);
  ep2_kernel<<<NN, 256, 0, stream>>>(vtmp, gsum, out);
}